// Round 1
// baseline (2926.728 us; speedup 1.0000x reference)
//
#include <hip/hip_runtime.h>
#include <math.h>

#define NEG_SLOPE 0.2f
#define EPS_DEN 1e-16f

// ---------- helpers ----------
__device__ __forceinline__ unsigned flipf(float f) {
    unsigned u = __float_as_uint(f);
    return (u & 0x80000000u) ? ~u : (u | 0x80000000u);
}
__device__ __forceinline__ float unflipf(unsigned u) {
    return (u & 0x80000000u) ? __uint_as_float(u ^ 0x80000000u) : __uint_as_float(~u);
}
__device__ __forceinline__ float leaky(float v) { return v > 0.f ? v : NEG_SLOPE * v; }

// ---------- GEMM1: h1[N,64] = x[N,512] @ W1[512,64], fused attention dots ----------
// block 256 = (16 col-groups of 4) x (16 rows)
__global__ __launch_bounds__(256) void gemm1_kernel(
    const float* __restrict__ x, const float* __restrict__ W1,
    const float* __restrict__ att_src, const float* __restrict__ att_dst,
    float* __restrict__ h1, float* __restrict__ a_src, float* __restrict__ a_dst, int N)
{
    int t  = threadIdx.x;
    int tx = t & 15;   // col group -> cols [tx*4, tx*4+4)
    int ty = t >> 4;   // row within tile
    int row = blockIdx.x * 16 + ty;
    if (row >= N) return;

    const float4* x4 = (const float4*)(x + (size_t)row * 512);
    const float4* W4 = (const float4*)W1;  // [512][16] of float4

    float4 acc = make_float4(0.f, 0.f, 0.f, 0.f);
#pragma unroll 4
    for (int k4 = 0; k4 < 128; ++k4) {
        float4 xv = x4[k4];
        float4 w0 = W4[(4 * k4 + 0) * 16 + tx];
        float4 w1 = W4[(4 * k4 + 1) * 16 + tx];
        float4 w2 = W4[(4 * k4 + 2) * 16 + tx];
        float4 w3 = W4[(4 * k4 + 3) * 16 + tx];
        acc.x += xv.x * w0.x + xv.y * w1.x + xv.z * w2.x + xv.w * w3.x;
        acc.y += xv.x * w0.y + xv.y * w1.y + xv.z * w2.y + xv.w * w3.y;
        acc.z += xv.x * w0.z + xv.y * w1.z + xv.z * w2.z + xv.w * w3.z;
        acc.w += xv.x * w0.w + xv.y * w1.w + xv.z * w2.w + xv.w * w3.w;
    }
    ((float4*)(h1 + (size_t)row * 64))[tx] = acc;

    // attention partials: flat att index == column index j (att[h*8+c], j=h*8+c)
    int j0 = tx * 4;
    float ps = acc.x * att_src[j0] + acc.y * att_src[j0 + 1] + acc.z * att_src[j0 + 2] + acc.w * att_src[j0 + 3];
    float pd = acc.x * att_dst[j0] + acc.y * att_dst[j0 + 1] + acc.z * att_dst[j0 + 2] + acc.w * att_dst[j0 + 3];
    ps += __shfl_xor(ps, 1);
    pd += __shfl_xor(pd, 1);
    if ((tx & 1) == 0) {
        int h = tx >> 1;
        a_src[(size_t)row * 8 + h] = ps;
        a_dst[(size_t)row * 8 + h] = pd;
    }
}

// ---------- L1 edge passes (H=8) ----------
__global__ __launch_bounds__(256) void edge_max_l1(
    const int* __restrict__ ei, const float* __restrict__ a_src, const float* __restrict__ a_dst,
    unsigned* __restrict__ m, int E, int Etot)
{
    int idx = blockIdx.x * blockDim.x + threadIdx.x;
    if (idx >= Etot) return;
    int s, d;
    if (idx < E) { s = ei[idx]; d = ei[E + idx]; } else { s = d = idx - E; }
    const float4* as = (const float4*)(a_src + (size_t)s * 8);
    const float4* ad = (const float4*)(a_dst + (size_t)d * 8);
    float4 s0 = as[0], s1 = as[1], d0 = ad[0], d1 = ad[1];
    float ev[8] = {s0.x + d0.x, s0.y + d0.y, s0.z + d0.z, s0.w + d0.w,
                   s1.x + d1.x, s1.y + d1.y, s1.z + d1.z, s1.w + d1.w};
#pragma unroll
    for (int h = 0; h < 8; ++h)
        atomicMax(&m[(size_t)d * 8 + h], flipf(leaky(ev[h])));
}

__global__ __launch_bounds__(256) void edge_sum_l1(
    const int* __restrict__ ei, const float* __restrict__ a_src, const float* __restrict__ a_dst,
    const unsigned* __restrict__ m, float* __restrict__ den, int E, int Etot)
{
    int idx = blockIdx.x * blockDim.x + threadIdx.x;
    if (idx >= Etot) return;
    int s, d;
    if (idx < E) { s = ei[idx]; d = ei[E + idx]; } else { s = d = idx - E; }
    const float4* as = (const float4*)(a_src + (size_t)s * 8);
    const float4* ad = (const float4*)(a_dst + (size_t)d * 8);
    float4 s0 = as[0], s1 = as[1], d0 = ad[0], d1 = ad[1];
    float ev[8] = {s0.x + d0.x, s0.y + d0.y, s0.z + d0.z, s0.w + d0.w,
                   s1.x + d1.x, s1.y + d1.y, s1.z + d1.z, s1.w + d1.w};
    const uint4* mm = (const uint4*)(m + (size_t)d * 8);
    uint4 m0 = mm[0], m1 = mm[1];
    float mv[8] = {unflipf(m0.x), unflipf(m0.y), unflipf(m0.z), unflipf(m0.w),
                   unflipf(m1.x), unflipf(m1.y), unflipf(m1.z), unflipf(m1.w)};
#pragma unroll
    for (int h = 0; h < 8; ++h)
        atomicAdd(&den[(size_t)d * 8 + h], expf(leaky(ev[h]) - mv[h]));
}

// wave per edge; lane = h*8 + c over 64 channels
__global__ __launch_bounds__(256) void edge_aggr_l1(
    const int* __restrict__ ei, const float* __restrict__ a_src, const float* __restrict__ a_dst,
    const unsigned* __restrict__ m, const float* __restrict__ den, const float* __restrict__ h1,
    float* __restrict__ out1, int E, int Etot)
{
    long long g = (long long)blockIdx.x * blockDim.x + threadIdx.x;
    int w = (int)(g >> 6), lane = (int)(g & 63);
    if (w >= Etot) return;
    int s, d;
    if (w < E) { s = ei[w]; d = ei[E + w]; } else { s = d = w - E; }
    int h = lane >> 3;
    float v = leaky(a_src[(size_t)s * 8 + h] + a_dst[(size_t)d * 8 + h]);
    float ex = expf(v - unflipf(m[(size_t)d * 8 + h]));
    float alpha = ex / (den[(size_t)d * 8 + h] + EPS_DEN);
    atomicAdd(&out1[(size_t)d * 64 + lane], alpha * h1[(size_t)s * 64 + lane]);
}

// ---------- finalize L1: h2 = relu(out1 + b1) ----------
__global__ __launch_bounds__(256) void finalize1_kernel(
    const float* __restrict__ out1, const float* __restrict__ b1,
    float* __restrict__ h2, long long total)
{
    long long g = (long long)blockIdx.x * blockDim.x + threadIdx.x;
    if (g >= total) return;
    int c = (int)(g & 63);
    float v = out1[g] + b1[c];
    h2[g] = v > 0.f ? v : 0.f;
}

// ---------- GEMM2: h3[N,40] = h2[N,64] @ W2[64,40], fused attention dots ----------
__global__ __launch_bounds__(256) void gemm2_kernel(
    const float* __restrict__ h2, const float* __restrict__ W2,
    const float* __restrict__ att_src2, const float* __restrict__ att_dst2,
    float* __restrict__ h3, float* __restrict__ a_src, float* __restrict__ a_dst, int N)
{
    __shared__ float Wl[64 * 40];
    int t = threadIdx.x;
    for (int i = t; i < 64 * 40; i += 256) Wl[i] = W2[i];
    __syncthreads();
    int lane = t & 63, wy = t >> 6;
    int row = blockIdx.x * 4 + wy;
    if (row >= N) return;
    float acc = 0.f;
    const float* hr = h2 + (size_t)row * 64;
    if (lane < 40) {
#pragma unroll 8
        for (int k = 0; k < 64; ++k) acc += hr[k] * Wl[k * 40 + lane];
        h3[(size_t)row * 40 + lane] = acc;
    }
    float ps = (lane < 40) ? acc * att_src2[lane] : 0.f;
    float pd = (lane < 40) ? acc * att_dst2[lane] : 0.f;
#pragma unroll
    for (int off = 32; off; off >>= 1) { ps += __shfl_down(ps, off); pd += __shfl_down(pd, off); }
    if (lane == 0) { a_src[row] = ps; a_dst[row] = pd; }
}

// ---------- L2 edge passes (H=1) ----------
__global__ __launch_bounds__(256) void edge_max_l2(
    const int* __restrict__ ei, const float* __restrict__ a_src, const float* __restrict__ a_dst,
    unsigned* __restrict__ m, int E, int Etot)
{
    int idx = blockIdx.x * blockDim.x + threadIdx.x;
    if (idx >= Etot) return;
    int s, d;
    if (idx < E) { s = ei[idx]; d = ei[E + idx]; } else { s = d = idx - E; }
    atomicMax(&m[d], flipf(leaky(a_src[s] + a_dst[d])));
}

__global__ __launch_bounds__(256) void edge_sum_l2(
    const int* __restrict__ ei, const float* __restrict__ a_src, const float* __restrict__ a_dst,
    const unsigned* __restrict__ m, float* __restrict__ den, int E, int Etot)
{
    int idx = blockIdx.x * blockDim.x + threadIdx.x;
    if (idx >= Etot) return;
    int s, d;
    if (idx < E) { s = ei[idx]; d = ei[E + idx]; } else { s = d = idx - E; }
    float v = leaky(a_src[s] + a_dst[d]);
    atomicAdd(&den[d], expf(v - unflipf(m[d])));
}

__global__ __launch_bounds__(256) void edge_aggr_l2(
    const int* __restrict__ ei, const float* __restrict__ a_src, const float* __restrict__ a_dst,
    const unsigned* __restrict__ m, const float* __restrict__ den, const float* __restrict__ h3,
    float* __restrict__ out2, int E, int Etot)
{
    long long g = (long long)blockIdx.x * blockDim.x + threadIdx.x;
    int w = (int)(g >> 6), lane = (int)(g & 63);
    if (w >= Etot) return;
    int s, d;
    if (w < E) { s = ei[w]; d = ei[E + w]; } else { s = d = w - E; }
    float v = leaky(a_src[s] + a_dst[d]);
    float ex = expf(v - unflipf(m[d]));
    float alpha = ex / (den[d] + EPS_DEN);
    if (lane < 40)
        atomicAdd(&out2[(size_t)d * 40 + lane], alpha * h3[(size_t)s * 40 + lane]);
}

// ---------- log_softmax over 40 classes, wave per row ----------
__global__ __launch_bounds__(256) void logsoftmax_kernel(
    const float* __restrict__ out2, const float* __restrict__ b2, float* __restrict__ y, int N)
{
    long long g = (long long)blockIdx.x * blockDim.x + threadIdx.x;
    int row = (int)(g >> 6), lane = (int)(g & 63);
    if (row >= N) return;
    float v = (lane < 40) ? out2[(size_t)row * 40 + lane] + b2[lane] : -INFINITY;
    float mx = v;
#pragma unroll
    for (int off = 32; off; off >>= 1) mx = fmaxf(mx, __shfl_down(mx, off));
    mx = __shfl(mx, 0);
    float ex = (lane < 40) ? expf(v - mx) : 0.f;
    float ss = ex;
#pragma unroll
    for (int off = 32; off; off >>= 1) ss += __shfl_down(ss, off);
    ss = __shfl(ss, 0);
    if (lane < 40) y[(size_t)row * 40 + lane] = v - mx - logf(ss);
}

// ---------- launch ----------
extern "C" void kernel_launch(void* const* d_in, const int* in_sizes, int n_in,
                              void* d_out, int out_size, void* d_ws, size_t ws_size,
                              hipStream_t stream)
{
    const float* x        = (const float*)d_in[0];
    const int*   ei       = (const int*)d_in[1];
    const float* W1       = (const float*)d_in[2];
    const float* att_src1 = (const float*)d_in[3];
    const float* att_dst1 = (const float*)d_in[4];
    const float* b1       = (const float*)d_in[5];
    const float* W2       = (const float*)d_in[6];
    const float* att_src2 = (const float*)d_in[7];
    const float* att_dst2 = (const float*)d_in[8];
    const float* b2       = (const float*)d_in[9];
    float* y = (float*)d_out;

    int N = in_sizes[0] / 512;
    int E = in_sizes[1] / 2;
    int Etot = E + N;

    char* p = (char*)d_ws;
    float* h1      = (float*)p;               p += (size_t)N * 64 * 4;
    float* a_src1a = (float*)p;               p += (size_t)N * 8 * 4;
    float* a_dst1a = (float*)p;               p += (size_t)N * 8 * 4;
    float* h2      = (float*)p;               p += (size_t)N * 64 * 4;
    float* h3      = (float*)p;               p += (size_t)N * 40 * 4;
    float* a_src2a = (float*)p;               p += (size_t)N * 4;
    float* a_dst2a = (float*)p;               p += (size_t)N * 4;
    char* zero_base = p;
    unsigned* m1   = (unsigned*)p;            p += (size_t)N * 8 * 4;
    float* den1    = (float*)p;               p += (size_t)N * 8 * 4;
    float* out1    = (float*)p;               p += (size_t)N * 64 * 4;
    unsigned* m2   = (unsigned*)p;            p += (size_t)N * 4;
    float* den2    = (float*)p;               p += (size_t)N * 4;
    float* out2    = (float*)p;               p += (size_t)N * 40 * 4;
    size_t zero_bytes = (size_t)(p - zero_base);

    hipMemsetAsync(zero_base, 0, zero_bytes, stream);

    // L1
    gemm1_kernel<<<(N + 15) / 16, 256, 0, stream>>>(x, W1, att_src1, att_dst1, h1, a_src1a, a_dst1a, N);
    edge_max_l1<<<(Etot + 255) / 256, 256, 0, stream>>>(ei, a_src1a, a_dst1a, m1, E, Etot);
    edge_sum_l1<<<(Etot + 255) / 256, 256, 0, stream>>>(ei, a_src1a, a_dst1a, m1, den1, E, Etot);
    {
        long long tot = (long long)Etot * 64;
        edge_aggr_l1<<<(unsigned)((tot + 255) / 256), 256, 0, stream>>>(ei, a_src1a, a_dst1a, m1, den1, h1, out1, E, Etot);
    }
    {
        long long tot = (long long)N * 64;
        finalize1_kernel<<<(unsigned)((tot + 255) / 256), 256, 0, stream>>>(out1, b1, h2, tot);
    }
    // L2
    gemm2_kernel<<<(N + 3) / 4, 256, 0, stream>>>(h2, W2, att_src2, att_dst2, h3, a_src2a, a_dst2a, N);
    edge_max_l2<<<(Etot + 255) / 256, 256, 0, stream>>>(ei, a_src2a, a_dst2a, m2, E, Etot);
    edge_sum_l2<<<(Etot + 255) / 256, 256, 0, stream>>>(ei, a_src2a, a_dst2a, m2, den2, E, Etot);
    {
        long long tot = (long long)Etot * 64;
        edge_aggr_l2<<<(unsigned)((tot + 255) / 256), 256, 0, stream>>>(ei, a_src2a, a_dst2a, m2, den2, h3, out2, E, Etot);
    }
    {
        long long tot = (long long)N * 64;
        logsoftmax_kernel<<<(unsigned)((tot + 255) / 256), 256, 0, stream>>>(out2, b2, y, N);
    }
}

// Round 2
// 1384.521 us; speedup vs baseline: 2.1139x; 2.1139x over previous
//
#include <hip/hip_runtime.h>
#include <math.h>

#define NEG_SLOPE 0.2f
#define EPS_DEN 1e-16f

__device__ __forceinline__ float leaky(float v) { return v > 0.f ? v : NEG_SLOPE * v; }

// ---------- GEMM1: h1[N,64] = x[N,512] @ W1[512,64], fused attention dots ----------
__global__ __launch_bounds__(256) void gemm1_kernel(
    const float* __restrict__ x, const float* __restrict__ W1,
    const float* __restrict__ att_src, const float* __restrict__ att_dst,
    float* __restrict__ h1, float* __restrict__ a_src, float* __restrict__ a_dst, int N)
{
    int t  = threadIdx.x;
    int tx = t & 15;   // col group -> cols [tx*4, tx*4+4)
    int ty = t >> 4;   // row within tile
    int row = blockIdx.x * 16 + ty;
    if (row >= N) return;

    const float4* x4 = (const float4*)(x + (size_t)row * 512);
    const float4* W4 = (const float4*)W1;  // [512][16] of float4

    float4 acc = make_float4(0.f, 0.f, 0.f, 0.f);
#pragma unroll 4
    for (int k4 = 0; k4 < 128; ++k4) {
        float4 xv = x4[k4];
        float4 w0 = W4[(4 * k4 + 0) * 16 + tx];
        float4 w1 = W4[(4 * k4 + 1) * 16 + tx];
        float4 w2 = W4[(4 * k4 + 2) * 16 + tx];
        float4 w3 = W4[(4 * k4 + 3) * 16 + tx];
        acc.x += xv.x * w0.x + xv.y * w1.x + xv.z * w2.x + xv.w * w3.x;
        acc.y += xv.x * w0.y + xv.y * w1.y + xv.z * w2.y + xv.w * w3.y;
        acc.z += xv.x * w0.z + xv.y * w1.z + xv.z * w2.z + xv.w * w3.z;
        acc.w += xv.x * w0.w + xv.y * w1.w + xv.z * w2.w + xv.w * w3.w;
    }
    ((float4*)(h1 + (size_t)row * 64))[tx] = acc;

    int j0 = tx * 4;
    float ps = acc.x * att_src[j0] + acc.y * att_src[j0 + 1] + acc.z * att_src[j0 + 2] + acc.w * att_src[j0 + 3];
    float pd = acc.x * att_dst[j0] + acc.y * att_dst[j0 + 1] + acc.z * att_dst[j0 + 2] + acc.w * att_dst[j0 + 3];
    ps += __shfl_xor(ps, 1);
    pd += __shfl_xor(pd, 1);
    if ((tx & 1) == 0) {
        int h = tx >> 1;
        a_src[(size_t)row * 8 + h] = ps;
        a_dst[(size_t)row * 8 + h] = pd;
    }
}

// ---------- CSR build ----------
__global__ __launch_bounds__(256) void deg_kernel(
    const int* __restrict__ ei, unsigned* __restrict__ deg, int E, int Etot)
{
    int idx = blockIdx.x * blockDim.x + threadIdx.x;
    if (idx >= Etot) return;
    int d = (idx < E) ? ei[E + idx] : (idx - E);
    atomicAdd(&deg[d], 1u);
}

// per-block exclusive scan of deg -> loc, block sums -> bsum
__global__ __launch_bounds__(256) void scanA_kernel(
    const unsigned* __restrict__ deg, unsigned* __restrict__ loc,
    unsigned* __restrict__ bsum, int N)
{
    __shared__ unsigned sh[256];
    int i = blockIdx.x * 256 + threadIdx.x;
    unsigned v = (i < N) ? deg[i] : 0u;
    sh[threadIdx.x] = v;
    __syncthreads();
    for (int off = 1; off < 256; off <<= 1) {
        unsigned u = (threadIdx.x >= (unsigned)off) ? sh[threadIdx.x - off] : 0u;
        __syncthreads();
        sh[threadIdx.x] += u;
        __syncthreads();
    }
    if (i < N) loc[i] = sh[threadIdx.x] - v;          // exclusive
    if (threadIdx.x == 255) bsum[blockIdx.x] = sh[255];
}

// single-block scan of bsum (in-place -> exclusive), with carry chunks of 1024
__global__ __launch_bounds__(1024) void scanB_kernel(unsigned* __restrict__ bsum, int nb)
{
    __shared__ unsigned sh[1024];
    int t = threadIdx.x;
    unsigned carry = 0;
    for (int base = 0; base < nb; base += 1024) {
        int i = base + t;
        unsigned v = (i < nb) ? bsum[i] : 0u;
        sh[t] = v;
        __syncthreads();
        for (int off = 1; off < 1024; off <<= 1) {
            unsigned u = (t >= off) ? sh[t - off] : 0u;
            __syncthreads();
            sh[t] += u;
            __syncthreads();
        }
        unsigned incl = sh[t];
        unsigned tot  = sh[1023];
        __syncthreads();
        if (i < nb) bsum[i] = incl - v + carry;
        carry += tot;
        __syncthreads();
    }
}

__global__ __launch_bounds__(256) void scanC_kernel(
    const unsigned* __restrict__ loc, const unsigned* __restrict__ bsum,
    unsigned* __restrict__ rowstart, unsigned* __restrict__ cursor, int N, int Etot)
{
    int i = blockIdx.x * 256 + threadIdx.x;
    if (i >= N) return;
    unsigned r = loc[i] + bsum[blockIdx.x];
    rowstart[i] = r;
    cursor[i] = r;
    if (i == 0) rowstart[N] = (unsigned)Etot;
}

__global__ __launch_bounds__(256) void scatter_kernel(
    const int* __restrict__ ei, unsigned* __restrict__ cursor,
    int* __restrict__ csr_src, int E, int Etot)
{
    int idx = blockIdx.x * blockDim.x + threadIdx.x;
    if (idx >= Etot) return;
    int s, d;
    if (idx < E) { s = ei[idx]; d = ei[E + idx]; } else { s = d = idx - E; }
    unsigned pos = atomicAdd(&cursor[d], 1u);
    csr_src[pos] = s;
}

// ---------- L1 aggregate: wave per dst node, online softmax, fused bias+relu ----------
__global__ __launch_bounds__(256) void aggr1_kernel(
    const unsigned* __restrict__ rowstart, const int* __restrict__ csr_src,
    const float* __restrict__ a_src, const float* __restrict__ a_dst,
    const float* __restrict__ h1, const float* __restrict__ b1,
    float* __restrict__ h2, int N)
{
    int g = blockIdx.x * 4 + (threadIdx.x >> 6);   // dst node = wave id
    int lane = threadIdx.x & 63;
    if (g >= N) return;
    int h = lane >> 3;                              // head for this channel
    float ad = a_dst[(size_t)g * 8 + h];
    unsigned k0 = rowstart[g], k1 = rowstart[g + 1];
    float m = -INFINITY, den = 0.f, acc = 0.f;
    for (unsigned k = k0; k < k1; ++k) {
        int s = csr_src[k];
        float e = leaky(a_src[(size_t)s * 8 + h] + ad);
        float mn = fmaxf(m, e);
        float scale = expf(m - mn);                 // m=-inf first iter -> 0
        float p = expf(e - mn);
        den = den * scale + p;
        acc = acc * scale + p * h1[(size_t)s * 64 + lane];
        m = mn;
    }
    float v = acc / (den + EPS_DEN) + b1[lane];
    h2[(size_t)g * 64 + lane] = v > 0.f ? v : 0.f;
}

// ---------- GEMM2: h3[N,40] = h2[N,64] @ W2[64,40], fused attention dots ----------
__global__ __launch_bounds__(256) void gemm2_kernel(
    const float* __restrict__ h2, const float* __restrict__ W2,
    const float* __restrict__ att_src2, const float* __restrict__ att_dst2,
    float* __restrict__ h3, float* __restrict__ a_src, float* __restrict__ a_dst, int N)
{
    __shared__ float Wl[64 * 40];
    int t = threadIdx.x;
    for (int i = t; i < 64 * 40; i += 256) Wl[i] = W2[i];
    __syncthreads();
    int lane = t & 63, wy = t >> 6;
    int row = blockIdx.x * 4 + wy;
    if (row >= N) return;
    float acc = 0.f;
    const float* hr = h2 + (size_t)row * 64;
    if (lane < 40) {
#pragma unroll 8
        for (int k = 0; k < 64; ++k) acc += hr[k] * Wl[k * 40 + lane];
        h3[(size_t)row * 40 + lane] = acc;
    }
    float ps = (lane < 40) ? acc * att_src2[lane] : 0.f;
    float pd = (lane < 40) ? acc * att_dst2[lane] : 0.f;
#pragma unroll
    for (int off = 32; off; off >>= 1) { ps += __shfl_down(ps, off); pd += __shfl_down(pd, off); }
    if (lane == 0) { a_src[row] = ps; a_dst[row] = pd; }
}

// ---------- L2 aggregate: wave per dst, online softmax, fused bias+log_softmax ----------
__global__ __launch_bounds__(256) void aggr2_kernel(
    const unsigned* __restrict__ rowstart, const int* __restrict__ csr_src,
    const float* __restrict__ a_src, const float* __restrict__ a_dst,
    const float* __restrict__ h3, const float* __restrict__ b2,
    float* __restrict__ y, int N)
{
    int g = blockIdx.x * 4 + (threadIdx.x >> 6);
    int lane = threadIdx.x & 63;
    if (g >= N) return;
    float ad = a_dst[g];
    unsigned k0 = rowstart[g], k1 = rowstart[g + 1];
    float m = -INFINITY, den = 0.f, acc = 0.f;
    for (unsigned k = k0; k < k1; ++k) {
        int s = csr_src[k];
        float e = leaky(a_src[s] + ad);
        float mn = fmaxf(m, e);
        float scale = expf(m - mn);
        float p = expf(e - mn);
        den = den * scale + p;
        float hv = (lane < 40) ? h3[(size_t)s * 40 + lane] : 0.f;
        acc = acc * scale + p * hv;
        m = mn;
    }
    float v = (lane < 40) ? (acc / (den + EPS_DEN) + b2[lane]) : -INFINITY;
    // log_softmax across 40 classes
    float mx = v;
#pragma unroll
    for (int off = 32; off; off >>= 1) mx = fmaxf(mx, __shfl_down(mx, off));
    mx = __shfl(mx, 0);
    float ex = (lane < 40) ? expf(v - mx) : 0.f;
    float ss = ex;
#pragma unroll
    for (int off = 32; off; off >>= 1) ss += __shfl_down(ss, off);
    ss = __shfl(ss, 0);
    if (lane < 40) y[(size_t)g * 40 + lane] = v - mx - logf(ss);
}

// ---------- launch ----------
extern "C" void kernel_launch(void* const* d_in, const int* in_sizes, int n_in,
                              void* d_out, int out_size, void* d_ws, size_t ws_size,
                              hipStream_t stream)
{
    const float* x        = (const float*)d_in[0];
    const int*   ei       = (const int*)d_in[1];
    const float* W1       = (const float*)d_in[2];
    const float* att_src1 = (const float*)d_in[3];
    const float* att_dst1 = (const float*)d_in[4];
    const float* b1       = (const float*)d_in[5];
    const float* W2       = (const float*)d_in[6];
    const float* att_src2 = (const float*)d_in[7];
    const float* att_dst2 = (const float*)d_in[8];
    const float* b2       = (const float*)d_in[9];
    float* y = (float*)d_out;

    int N = in_sizes[0] / 512;
    int E = in_sizes[1] / 2;
    int Etot = E + N;
    int nb = (N + 255) / 256;

    char* p = (char*)d_ws;
    float* h1       = (float*)p;   p += (size_t)N * 64 * 4;
    float* a_src1a  = (float*)p;   p += (size_t)N * 8 * 4;
    float* a_dst1a  = (float*)p;   p += (size_t)N * 8 * 4;
    float* h2       = (float*)p;   p += (size_t)N * 64 * 4;
    float* h3       = (float*)p;   p += (size_t)N * 40 * 4;
    float* a_src2a  = (float*)p;   p += (size_t)N * 4;
    float* a_dst2a  = (float*)p;   p += (size_t)N * 4;
    unsigned* deg   = (unsigned*)p; p += (size_t)N * 4;
    unsigned* loc   = (unsigned*)p; p += (size_t)N * 4;
    unsigned* bsum  = (unsigned*)p; p += (size_t)nb * 4;
    unsigned* rowstart = (unsigned*)p; p += (size_t)(N + 1) * 4;
    unsigned* cursor   = (unsigned*)p; p += (size_t)N * 4;
    int* csr_src    = (int*)p;     p += (size_t)Etot * 4;

    hipMemsetAsync(deg, 0, (size_t)N * 4, stream);

    // GEMM1 + attention logits
    gemm1_kernel<<<(N + 15) / 16, 256, 0, stream>>>(x, W1, att_src1, att_dst1, h1, a_src1a, a_dst1a, N);

    // CSR build (shared by both layers)
    deg_kernel<<<(Etot + 255) / 256, 256, 0, stream>>>(ei, deg, E, Etot);
    scanA_kernel<<<nb, 256, 0, stream>>>(deg, loc, bsum, N);
    scanB_kernel<<<1, 1024, 0, stream>>>(bsum, nb);
    scanC_kernel<<<nb, 256, 0, stream>>>(loc, bsum, rowstart, cursor, N, Etot);
    scatter_kernel<<<(Etot + 255) / 256, 256, 0, stream>>>(ei, cursor, csr_src, E, Etot);

    // L1 aggregate (online softmax) + bias + relu
    aggr1_kernel<<<(N + 3) / 4, 256, 0, stream>>>(rowstart, csr_src, a_src1a, a_dst1a, h1, b1, h2, N);

    // GEMM2 + attention logits
    gemm2_kernel<<<(N + 3) / 4, 256, 0, stream>>>(h2, W2, att_src2, att_dst2, h3, a_src2a, a_dst2a, N);

    // L2 aggregate + bias + log_softmax
    aggr2_kernel<<<(N + 3) / 4, 256, 0, stream>>>(rowstart, csr_src, a_src2a, a_dst2a, h3, b2, y, N);
}

// Round 3
// 958.888 us; speedup vs baseline: 3.0522x; 1.4439x over previous
//
#include <hip/hip_runtime.h>
#include <math.h>

#define NEG_SLOPE 0.2f
#define EPS_DEN 1e-16f

__device__ __forceinline__ float leaky(float v) { return v > 0.f ? v : NEG_SLOPE * v; }

typedef __attribute__((ext_vector_type(8))) short bf16x8;
typedef __attribute__((ext_vector_type(4))) float f32x4;

__device__ __forceinline__ unsigned bf16rne(float f) {
    unsigned u = __float_as_uint(f);
    return (u + 0x7FFFu + ((u >> 16) & 1u)) >> 16;
}
__device__ __forceinline__ unsigned pack2(float a, float b) {
    return bf16rne(a) | (bf16rne(b) << 16);
}

// ---------- GEMM1 (MFMA): h1[N,64] = x[N,512] @ W1[512,64] ----------
// block 256 = 4 waves; M-tile 128 (wave -> 32 rows), N=64 full, BK=32, 16 chunks.
__global__ __launch_bounds__(256) void gemm1_mfma(
    const float* __restrict__ x, const float* __restrict__ W1,
    float* __restrict__ h1, int N)
{
    __shared__ __align__(16) unsigned short As[128 * 40];  // [row][k] pad 40
    __shared__ __align__(16) unsigned short Bs[64 * 40];   // [col][k] pad 40

    const int t = threadIdx.x;
    const int w = t >> 6;          // wave 0..3
    const int lane = t & 63;
    const int m16 = lane & 15;
    const int quad = lane >> 4;
    const int rowBase = blockIdx.x * 128;

    f32x4 acc[2][4];
#pragma unroll
    for (int i = 0; i < 2; ++i)
#pragma unroll
        for (int j = 0; j < 4; ++j) acc[i][j] = (f32x4){0.f, 0.f, 0.f, 0.f};

    const float4* x4 = (const float4*)x;

#pragma unroll 1
    for (int chunk = 0; chunk < 16; ++chunk) {
        const int k0 = chunk * 32;
        // ---- stage A: 128 rows x 32 k (fp32 -> bf16) ----
#pragma unroll
        for (int r = 0; r < 4; ++r) {
            int e = t + r * 256;           // 0..1023
            int row = e >> 3;              // 0..127
            int kg = e & 7;                // float4 group within chunk
            int grow = rowBase + row;
            float4 v = make_float4(0.f, 0.f, 0.f, 0.f);
            if (grow < N) v = x4[(size_t)grow * 128 + (k0 >> 2) + kg];
            uint2 pk = make_uint2(pack2(v.x, v.y), pack2(v.z, v.w));
            *(uint2*)&As[row * 40 + kg * 4] = pk;
        }
        // ---- stage B transposed: Bs[col][k] ----
        {
            int c = lane;                  // column 0..63
            int jb = w * 8;                // k sub-range per wave
            float f[8];
#pragma unroll
            for (int j = 0; j < 8; ++j) f[j] = W1[(size_t)(k0 + jb + j) * 64 + c];
            uint4 pk;
            pk.x = pack2(f[0], f[1]); pk.y = pack2(f[2], f[3]);
            pk.z = pack2(f[4], f[5]); pk.w = pack2(f[6], f[7]);
            *(uint4*)&Bs[c * 40 + jb] = pk;
        }
        __syncthreads();
        // ---- compute ----
        bf16x8 a0 = *(const bf16x8*)&As[(w * 32 + m16) * 40 + quad * 8];
        bf16x8 a1 = *(const bf16x8*)&As[(w * 32 + 16 + m16) * 40 + quad * 8];
#pragma unroll
        for (int j = 0; j < 4; ++j) {
            bf16x8 b = *(const bf16x8*)&Bs[(j * 16 + m16) * 40 + quad * 8];
            acc[0][j] = __builtin_amdgcn_mfma_f32_16x16x32_bf16(a0, b, acc[0][j], 0, 0, 0);
            acc[1][j] = __builtin_amdgcn_mfma_f32_16x16x32_bf16(a1, b, acc[1][j], 0, 0, 0);
        }
        __syncthreads();
    }

    // ---- epilogue: C/D layout col=lane&15, row=quad*4+reg ----
#pragma unroll
    for (int i = 0; i < 2; ++i)
#pragma unroll
        for (int reg = 0; reg < 4; ++reg) {
            int r = rowBase + w * 32 + i * 16 + quad * 4 + reg;
            if (r < N) {
#pragma unroll
                for (int j = 0; j < 4; ++j)
                    h1[(size_t)r * 64 + j * 16 + m16] = acc[i][j][reg];
            }
        }
}

// ---------- attention dots for L1: a_src/a_dst[N,8] from h1 ----------
__global__ __launch_bounds__(256) void att1_kernel(
    const float* __restrict__ h1, const float* __restrict__ att_src,
    const float* __restrict__ att_dst, float* __restrict__ a_src,
    float* __restrict__ a_dst, int N)
{
    int g = blockIdx.x * 256 + threadIdx.x;   // one (row, head) per thread
    int row = g >> 3, h = g & 7;
    if (row >= N) return;
    const float* hp = h1 + (size_t)row * 64 + h * 8;
    float ps = 0.f, pd = 0.f;
#pragma unroll
    for (int c = 0; c < 8; ++c) {
        float v = hp[c];
        ps += v * att_src[h * 8 + c];
        pd += v * att_dst[h * 8 + c];
    }
    a_src[(size_t)row * 8 + h] = ps;
    a_dst[(size_t)row * 8 + h] = pd;
}

// ---------- CSR build ----------
__global__ __launch_bounds__(256) void deg_kernel(
    const int* __restrict__ ei, unsigned* __restrict__ deg, int E, int Etot)
{
    int idx = blockIdx.x * blockDim.x + threadIdx.x;
    if (idx >= Etot) return;
    int d = (idx < E) ? ei[E + idx] : (idx - E);
    atomicAdd(&deg[d], 1u);
}

__global__ __launch_bounds__(256) void scanA_kernel(
    const unsigned* __restrict__ deg, unsigned* __restrict__ loc,
    unsigned* __restrict__ bsum, int N)
{
    __shared__ unsigned sh[256];
    int i = blockIdx.x * 256 + threadIdx.x;
    unsigned v = (i < N) ? deg[i] : 0u;
    sh[threadIdx.x] = v;
    __syncthreads();
    for (int off = 1; off < 256; off <<= 1) {
        unsigned u = (threadIdx.x >= (unsigned)off) ? sh[threadIdx.x - off] : 0u;
        __syncthreads();
        sh[threadIdx.x] += u;
        __syncthreads();
    }
    if (i < N) loc[i] = sh[threadIdx.x] - v;
    if (threadIdx.x == 255) bsum[blockIdx.x] = sh[255];
}

__global__ __launch_bounds__(1024) void scanB_kernel(unsigned* __restrict__ bsum, int nb)
{
    __shared__ unsigned sh[1024];
    int t = threadIdx.x;
    unsigned carry = 0;
    for (int base = 0; base < nb; base += 1024) {
        int i = base + t;
        unsigned v = (i < nb) ? bsum[i] : 0u;
        sh[t] = v;
        __syncthreads();
        for (int off = 1; off < 1024; off <<= 1) {
            unsigned u = (t >= off) ? sh[t - off] : 0u;
            __syncthreads();
            sh[t] += u;
            __syncthreads();
        }
        unsigned incl = sh[t];
        unsigned tot  = sh[1023];
        __syncthreads();
        if (i < nb) bsum[i] = incl - v + carry;
        carry += tot;
        __syncthreads();
    }
}

__global__ __launch_bounds__(256) void scanC_kernel(
    const unsigned* __restrict__ loc, const unsigned* __restrict__ bsum,
    unsigned* __restrict__ rowstart, unsigned* __restrict__ cursor, int N, int Etot)
{
    int i = blockIdx.x * 256 + threadIdx.x;
    if (i >= N) return;
    unsigned r = loc[i] + bsum[blockIdx.x];
    rowstart[i] = r;
    cursor[i] = r;
    if (i == 0) rowstart[N] = (unsigned)Etot;
}

__global__ __launch_bounds__(256) void scatter_kernel(
    const int* __restrict__ ei, unsigned* __restrict__ cursor,
    int* __restrict__ csr_src, int E, int Etot)
{
    int idx = blockIdx.x * blockDim.x + threadIdx.x;
    if (idx >= Etot) return;
    int s, d;
    if (idx < E) { s = ei[idx]; d = ei[E + idx]; } else { s = d = idx - E; }
    unsigned pos = atomicAdd(&cursor[d], 1u);
    csr_src[pos] = s;
}

// ---------- L1 aggregate: wave per dst node, online softmax, fused bias+relu ----------
__global__ __launch_bounds__(256) void aggr1_kernel(
    const unsigned* __restrict__ rowstart, const int* __restrict__ csr_src,
    const float* __restrict__ a_src, const float* __restrict__ a_dst,
    const float* __restrict__ h1, const float* __restrict__ b1,
    float* __restrict__ h2, int N)
{
    int g = blockIdx.x * 4 + (threadIdx.x >> 6);
    int lane = threadIdx.x & 63;
    if (g >= N) return;
    int h = lane >> 3;
    float ad = a_dst[(size_t)g * 8 + h];
    unsigned k0 = rowstart[g], k1 = rowstart[g + 1];
    float m = -INFINITY, den = 0.f, acc = 0.f;
    for (unsigned k = k0; k < k1; ++k) {
        int s = csr_src[k];
        float e = leaky(a_src[(size_t)s * 8 + h] + ad);
        float mn = fmaxf(m, e);
        float scale = expf(m - mn);
        float p = expf(e - mn);
        den = den * scale + p;
        acc = acc * scale + p * h1[(size_t)s * 64 + lane];
        m = mn;
    }
    float v = acc / (den + EPS_DEN) + b1[lane];
    h2[(size_t)g * 64 + lane] = v > 0.f ? v : 0.f;
}

// ---------- GEMM2: h3[N,40] = h2[N,64] @ W2[64,40], fused attention dots ----------
__global__ __launch_bounds__(256) void gemm2_kernel(
    const float* __restrict__ h2, const float* __restrict__ W2,
    const float* __restrict__ att_src2, const float* __restrict__ att_dst2,
    float* __restrict__ h3, float* __restrict__ a_src, float* __restrict__ a_dst, int N)
{
    __shared__ float Wl[64 * 40];
    int t = threadIdx.x;
    for (int i = t; i < 64 * 40; i += 256) Wl[i] = W2[i];
    __syncthreads();
    int lane = t & 63, wy = t >> 6;
    int row = blockIdx.x * 4 + wy;
    if (row >= N) return;
    float acc = 0.f;
    const float* hr = h2 + (size_t)row * 64;
    if (lane < 40) {
#pragma unroll 8
        for (int k = 0; k < 64; ++k) acc += hr[k] * Wl[k * 40 + lane];
        h3[(size_t)row * 40 + lane] = acc;
    }
    float ps = (lane < 40) ? acc * att_src2[lane] : 0.f;
    float pd = (lane < 40) ? acc * att_dst2[lane] : 0.f;
#pragma unroll
    for (int off = 32; off; off >>= 1) { ps += __shfl_down(ps, off); pd += __shfl_down(pd, off); }
    if (lane == 0) { a_src[row] = ps; a_dst[row] = pd; }
}

// ---------- L2 aggregate: wave per dst, online softmax, fused bias+log_softmax ----------
__global__ __launch_bounds__(256) void aggr2_kernel(
    const unsigned* __restrict__ rowstart, const int* __restrict__ csr_src,
    const float* __restrict__ a_src, const float* __restrict__ a_dst,
    const float* __restrict__ h3, const float* __restrict__ b2,
    float* __restrict__ y, int N)
{
    int g = blockIdx.x * 4 + (threadIdx.x >> 6);
    int lane = threadIdx.x & 63;
    if (g >= N) return;
    float ad = a_dst[g];
    unsigned k0 = rowstart[g], k1 = rowstart[g + 1];
    float m = -INFINITY, den = 0.f, acc = 0.f;
    for (unsigned k = k0; k < k1; ++k) {
        int s = csr_src[k];
        float e = leaky(a_src[s] + ad);
        float mn = fmaxf(m, e);
        float scale = expf(m - mn);
        float p = expf(e - mn);
        den = den * scale + p;
        float hv = (lane < 40) ? h3[(size_t)s * 40 + lane] : 0.f;
        acc = acc * scale + p * hv;
        m = mn;
    }
    float v = (lane < 40) ? (acc / (den + EPS_DEN) + b2[lane]) : -INFINITY;
    float mx = v;
#pragma unroll
    for (int off = 32; off; off >>= 1) mx = fmaxf(mx, __shfl_down(mx, off));
    mx = __shfl(mx, 0);
    float ex = (lane < 40) ? expf(v - mx) : 0.f;
    float ss = ex;
#pragma unroll
    for (int off = 32; off; off >>= 1) ss += __shfl_down(ss, off);
    ss = __shfl(ss, 0);
    if (lane < 40) y[(size_t)g * 40 + lane] = v - mx - logf(ss);
}

// ---------- launch ----------
extern "C" void kernel_launch(void* const* d_in, const int* in_sizes, int n_in,
                              void* d_out, int out_size, void* d_ws, size_t ws_size,
                              hipStream_t stream)
{
    const float* x        = (const float*)d_in[0];
    const int*   ei       = (const int*)d_in[1];
    const float* W1       = (const float*)d_in[2];
    const float* att_src1 = (const float*)d_in[3];
    const float* att_dst1 = (const float*)d_in[4];
    const float* b1       = (const float*)d_in[5];
    const float* W2       = (const float*)d_in[6];
    const float* att_src2 = (const float*)d_in[7];
    const float* att_dst2 = (const float*)d_in[8];
    const float* b2       = (const float*)d_in[9];
    float* y = (float*)d_out;

    int N = in_sizes[0] / 512;
    int E = in_sizes[1] / 2;
    int Etot = E + N;
    int nb = (N + 255) / 256;

    char* p = (char*)d_ws;
    float* h1       = (float*)p;   p += (size_t)N * 64 * 4;
    float* a_src1a  = (float*)p;   p += (size_t)N * 8 * 4;
    float* a_dst1a  = (float*)p;   p += (size_t)N * 8 * 4;
    float* h2       = (float*)p;   p += (size_t)N * 64 * 4;
    float* h3       = (float*)p;   p += (size_t)N * 40 * 4;
    float* a_src2a  = (float*)p;   p += (size_t)N * 4;
    float* a_dst2a  = (float*)p;   p += (size_t)N * 4;
    unsigned* deg   = (unsigned*)p; p += (size_t)N * 4;
    unsigned* loc   = (unsigned*)p; p += (size_t)N * 4;
    unsigned* bsum  = (unsigned*)p; p += (size_t)nb * 4;
    unsigned* rowstart = (unsigned*)p; p += (size_t)(N + 1) * 4;
    unsigned* cursor   = (unsigned*)p; p += (size_t)N * 4;
    int* csr_src    = (int*)p;     p += (size_t)Etot * 4;

    hipMemsetAsync(deg, 0, (size_t)N * 4, stream);

    // GEMM1 (MFMA) then attention logits
    gemm1_mfma<<<(N + 127) / 128, 256, 0, stream>>>(x, W1, h1, N);
    att1_kernel<<<(N * 8 + 255) / 256, 256, 0, stream>>>(h1, att_src1, att_dst1, a_src1a, a_dst1a, N);

    // CSR build (shared by both layers)
    deg_kernel<<<(Etot + 255) / 256, 256, 0, stream>>>(ei, deg, E, Etot);
    scanA_kernel<<<nb, 256, 0, stream>>>(deg, loc, bsum, N);
    scanB_kernel<<<1, 1024, 0, stream>>>(bsum, nb);
    scanC_kernel<<<nb, 256, 0, stream>>>(loc, bsum, rowstart, cursor, N, Etot);
    scatter_kernel<<<(Etot + 255) / 256, 256, 0, stream>>>(ei, cursor, csr_src, E, Etot);

    // L1 aggregate (online softmax) + bias + relu
    aggr1_kernel<<<(N + 3) / 4, 256, 0, stream>>>(rowstart, csr_src, a_src1a, a_dst1a, h1, b1, h2, N);

    // GEMM2 + attention logits
    gemm2_kernel<<<(N + 3) / 4, 256, 0, stream>>>(h2, W2, att_src2, att_dst2, h3, a_src2a, a_dst2a, N);

    // L2 aggregate + bias + log_softmax
    aggr2_kernel<<<(N + 3) / 4, 256, 0, stream>>>(rowstart, csr_src, a_src2a, a_dst2a, h3, b2, y, N);
}